// Round 2
// baseline (7223.795 us; speedup 1.0000x reference)
//
#include <hip/hip_runtime.h>
#include <hip/hip_bf16.h>

#define NN 16384
#define NE 131072
#define L 256
#define SSTEPS 4
#define OUTD 128

__device__ __forceinline__ float wave_sum(float v) {
#pragma unroll
  for (int o = 32; o > 0; o >>= 1) v += __shfl_xor(v, o);
  return v;
}

// ---------------------------------------------------------------------------
// Embedder: rows x K -> MLP(K->256 relu ->256) -> LayerNorm -> dst (fp32)
// One block: R rows, 256 threads (thread t owns output column t).
// ---------------------------------------------------------------------------
template <int K, int R>
__global__ __launch_bounds__(256) void embed_kernel(
    const float* __restrict__ x_in, const float* __restrict__ W0,
    const float* __restrict__ b0, const float* __restrict__ W1,
    const float* __restrict__ b1, const float* __restrict__ ls,
    const float* __restrict__ lb, float* __restrict__ dst) {
  __shared__ __align__(16) float xs[R][K < 4 ? 4 : K];
  __shared__ __align__(16) float ys[R][L];
  const int t = threadIdx.x;
  const int r0 = blockIdx.x * R;

  if (t < K * R) xs[t / K][t % K] = x_in[(size_t)r0 * K + t];
  __syncthreads();

  float acc[R];
  {
    const float b = b0[t];
#pragma unroll
    for (int r = 0; r < R; ++r) acc[r] = b;
  }
#pragma unroll
  for (int k = 0; k < K; ++k) {
    const float w = W0[k * L + t];
#pragma unroll
    for (int r = 0; r < R; ++r) acc[r] = fmaf(xs[r][k], w, acc[r]);
  }
#pragma unroll
  for (int r = 0; r < R; ++r) ys[r][t] = fmaxf(acc[r], 0.f);
  __syncthreads();

  float acc2[R];
  {
    const float b = b1[t];
#pragma unroll
    for (int r = 0; r < R; ++r) acc2[r] = b;
  }
  for (int k = 0; k < L; k += 4) {
    const float w0 = W1[(k + 0) * L + t];
    const float w1 = W1[(k + 1) * L + t];
    const float w2 = W1[(k + 2) * L + t];
    const float w3 = W1[(k + 3) * L + t];
#pragma unroll
    for (int r = 0; r < R; ++r) {
      const float4 h = *(const float4*)&ys[r][k];
      acc2[r] = fmaf(h.x, w0, acc2[r]);
      acc2[r] = fmaf(h.y, w1, acc2[r]);
      acc2[r] = fmaf(h.z, w2, acc2[r]);
      acc2[r] = fmaf(h.w, w3, acc2[r]);
    }
  }
  __syncthreads();
#pragma unroll
  for (int r = 0; r < R; ++r) ys[r][t] = acc2[r];
  __syncthreads();

  const int w = t >> 6, l = t & 63;
  constexpr int RPW = R / 4;
#pragma unroll
  for (int rr = 0; rr < RPW; ++rr) {
    const int r = w * RPW + rr;
    float v[4];
#pragma unroll
    for (int j = 0; j < 4; ++j) v[j] = ys[r][l + 64 * j];
    const float mu = wave_sum(v[0] + v[1] + v[2] + v[3]) * (1.f / 256.f);
    float sq = 0.f;
#pragma unroll
    for (int j = 0; j < 4; ++j) {
      v[j] -= mu;
      sq += v[j] * v[j];
    }
    const float rstd = rsqrtf(wave_sum(sq) * (1.f / 256.f) + 1e-6f);
    const size_t row = (size_t)(r0 + r);
#pragma unroll
    for (int j = 0; j < 4; ++j) {
      const int c = l + 64 * j;
      dst[row * L + c] = v[j] * rstd * ls[c] + lb[c];
    }
  }
}

// ---------------------------------------------------------------------------
// Processor edge step: x = [edges[e], nodes[snd], nodes[rcv]] (768) ->
// MLP(768->256 relu ->256) -> LN -> edges += new_e ; atomicAdd agg[rcv]
// ---------------------------------------------------------------------------
template <int R>
__global__ __launch_bounds__(256) void edge_step_kernel(
    const float* __restrict__ nodes, float* __restrict__ edges,
    float* __restrict__ agg, const int* __restrict__ senders,
    const int* __restrict__ receivers, const float* __restrict__ W0,
    const float* __restrict__ b0, const float* __restrict__ W1,
    const float* __restrict__ b1, const float* __restrict__ ls,
    const float* __restrict__ lb) {
  __shared__ __align__(16) float xs[R][3 * L];
  __shared__ __align__(16) float ys[R][L];
  __shared__ int rcv_s[R];
  const int t = threadIdx.x;
  const int e0 = blockIdx.x * R;

#pragma unroll
  for (int r = 0; r < R; ++r) {
    const int e = e0 + r;
    const int sn = senders[e];
    const int rc = receivers[e];
    if (t == 0) rcv_s[r] = rc;
    xs[r][t] = edges[(size_t)e * L + t];
    xs[r][L + t] = nodes[(size_t)sn * L + t];
    xs[r][2 * L + t] = nodes[(size_t)rc * L + t];
  }
  __syncthreads();

  float acc[R];
  {
    const float b = b0[t];
#pragma unroll
    for (int r = 0; r < R; ++r) acc[r] = b;
  }
  for (int k = 0; k < 3 * L; k += 4) {
    const float w0 = W0[(k + 0) * L + t];
    const float w1 = W0[(k + 1) * L + t];
    const float w2 = W0[(k + 2) * L + t];
    const float w3 = W0[(k + 3) * L + t];
#pragma unroll
    for (int r = 0; r < R; ++r) {
      const float4 x = *(const float4*)&xs[r][k];
      acc[r] = fmaf(x.x, w0, acc[r]);
      acc[r] = fmaf(x.y, w1, acc[r]);
      acc[r] = fmaf(x.z, w2, acc[r]);
      acc[r] = fmaf(x.w, w3, acc[r]);
    }
  }
#pragma unroll
  for (int r = 0; r < R; ++r) ys[r][t] = fmaxf(acc[r], 0.f);
  __syncthreads();

  float acc2[R];
  {
    const float b = b1[t];
#pragma unroll
    for (int r = 0; r < R; ++r) acc2[r] = b;
  }
  for (int k = 0; k < L; k += 4) {
    const float w0 = W1[(k + 0) * L + t];
    const float w1 = W1[(k + 1) * L + t];
    const float w2 = W1[(k + 2) * L + t];
    const float w3 = W1[(k + 3) * L + t];
#pragma unroll
    for (int r = 0; r < R; ++r) {
      const float4 h = *(const float4*)&ys[r][k];
      acc2[r] = fmaf(h.x, w0, acc2[r]);
      acc2[r] = fmaf(h.y, w1, acc2[r]);
      acc2[r] = fmaf(h.z, w2, acc2[r]);
      acc2[r] = fmaf(h.w, w3, acc2[r]);
    }
  }
  __syncthreads();
#pragma unroll
  for (int r = 0; r < R; ++r) ys[r][t] = acc2[r];
  __syncthreads();

  const int w = t >> 6, l = t & 63;
  constexpr int RPW = R / 4;
#pragma unroll
  for (int rr = 0; rr < RPW; ++rr) {
    const int r = w * RPW + rr;
    float v[4];
#pragma unroll
    for (int j = 0; j < 4; ++j) v[j] = ys[r][l + 64 * j];
    const float mu = wave_sum(v[0] + v[1] + v[2] + v[3]) * (1.f / 256.f);
    float sq = 0.f;
#pragma unroll
    for (int j = 0; j < 4; ++j) {
      v[j] -= mu;
      sq += v[j] * v[j];
    }
    const float rstd = rsqrtf(wave_sum(sq) * (1.f / 256.f) + 1e-6f);
    const size_t e = (size_t)(e0 + r);
    const int rc = rcv_s[r];
#pragma unroll
    for (int j = 0; j < 4; ++j) {
      const int c = l + 64 * j;
      const float ne = v[j] * rstd * ls[c] + lb[c];
      edges[e * L + c] = xs[r][c] + ne;  // residual (xs still holds old edge)
      atomicAdd(agg + (size_t)rc * L + c, ne);
    }
  }
}

// ---------------------------------------------------------------------------
// Processor node step: x = [nodes[n], agg[n]] (512) -> MLP -> LN -> nodes +=
// ---------------------------------------------------------------------------
template <int R>
__global__ __launch_bounds__(256) void node_step_kernel(
    float* __restrict__ nodes, const float* __restrict__ agg,
    const float* __restrict__ W0, const float* __restrict__ b0,
    const float* __restrict__ W1, const float* __restrict__ b1,
    const float* __restrict__ ls, const float* __restrict__ lb) {
  __shared__ __align__(16) float xs[R][2 * L];
  __shared__ __align__(16) float ys[R][L];
  const int t = threadIdx.x;
  const int n0 = blockIdx.x * R;

#pragma unroll
  for (int r = 0; r < R; ++r) {
    xs[r][t] = nodes[(size_t)(n0 + r) * L + t];
    xs[r][L + t] = agg[(size_t)(n0 + r) * L + t];
  }
  __syncthreads();

  float acc[R];
  {
    const float b = b0[t];
#pragma unroll
    for (int r = 0; r < R; ++r) acc[r] = b;
  }
  for (int k = 0; k < 2 * L; k += 4) {
    const float w0 = W0[(k + 0) * L + t];
    const float w1 = W0[(k + 1) * L + t];
    const float w2 = W0[(k + 2) * L + t];
    const float w3 = W0[(k + 3) * L + t];
#pragma unroll
    for (int r = 0; r < R; ++r) {
      const float4 x = *(const float4*)&xs[r][k];
      acc[r] = fmaf(x.x, w0, acc[r]);
      acc[r] = fmaf(x.y, w1, acc[r]);
      acc[r] = fmaf(x.z, w2, acc[r]);
      acc[r] = fmaf(x.w, w3, acc[r]);
    }
  }
#pragma unroll
  for (int r = 0; r < R; ++r) ys[r][t] = fmaxf(acc[r], 0.f);
  __syncthreads();

  float acc2[R];
  {
    const float b = b1[t];
#pragma unroll
    for (int r = 0; r < R; ++r) acc2[r] = b;
  }
  for (int k = 0; k < L; k += 4) {
    const float w0 = W1[(k + 0) * L + t];
    const float w1 = W1[(k + 1) * L + t];
    const float w2 = W1[(k + 2) * L + t];
    const float w3 = W1[(k + 3) * L + t];
#pragma unroll
    for (int r = 0; r < R; ++r) {
      const float4 h = *(const float4*)&ys[r][k];
      acc2[r] = fmaf(h.x, w0, acc2[r]);
      acc2[r] = fmaf(h.y, w1, acc2[r]);
      acc2[r] = fmaf(h.z, w2, acc2[r]);
      acc2[r] = fmaf(h.w, w3, acc2[r]);
    }
  }
  __syncthreads();
#pragma unroll
  for (int r = 0; r < R; ++r) ys[r][t] = acc2[r];
  __syncthreads();

  const int w = t >> 6, l = t & 63;
  constexpr int RPW = R / 4;
#pragma unroll
  for (int rr = 0; rr < RPW; ++rr) {
    const int r = w * RPW + rr;
    float v[4];
#pragma unroll
    for (int j = 0; j < 4; ++j) v[j] = ys[r][l + 64 * j];
    const float mu = wave_sum(v[0] + v[1] + v[2] + v[3]) * (1.f / 256.f);
    float sq = 0.f;
#pragma unroll
    for (int j = 0; j < 4; ++j) {
      v[j] -= mu;
      sq += v[j] * v[j];
    }
    const float rstd = rsqrtf(wave_sum(sq) * (1.f / 256.f) + 1e-6f);
    const size_t row = (size_t)(n0 + r);
#pragma unroll
    for (int j = 0; j < 4; ++j) {
      const int c = l + 64 * j;
      const float nn = v[j] * rstd * ls[c] + lb[c];
      nodes[row * L + c] = xs[r][c] + nn;  // residual
    }
  }
}

// ---------------------------------------------------------------------------
// Decoder: nodes (256) -> MLP(256->256 relu ->128), no LN, fp32 out
// ---------------------------------------------------------------------------
template <int R>
__global__ __launch_bounds__(256) void decoder_kernel(
    const float* __restrict__ nodes, const float* __restrict__ W0,
    const float* __restrict__ b0, const float* __restrict__ W1,
    const float* __restrict__ b1, float* __restrict__ out) {
  __shared__ __align__(16) float xs[R][L];
  __shared__ __align__(16) float hs[R][L];
  const int t = threadIdx.x;
  const int n0 = blockIdx.x * R;

#pragma unroll
  for (int r = 0; r < R; ++r) xs[r][t] = nodes[(size_t)(n0 + r) * L + t];
  __syncthreads();

  float acc[R];
  {
    const float b = b0[t];
#pragma unroll
    for (int r = 0; r < R; ++r) acc[r] = b;
  }
  for (int k = 0; k < L; k += 4) {
    const float w0 = W0[(k + 0) * L + t];
    const float w1 = W0[(k + 1) * L + t];
    const float w2 = W0[(k + 2) * L + t];
    const float w3 = W0[(k + 3) * L + t];
#pragma unroll
    for (int r = 0; r < R; ++r) {
      const float4 x = *(const float4*)&xs[r][k];
      acc[r] = fmaf(x.x, w0, acc[r]);
      acc[r] = fmaf(x.y, w1, acc[r]);
      acc[r] = fmaf(x.z, w2, acc[r]);
      acc[r] = fmaf(x.w, w3, acc[r]);
    }
  }
#pragma unroll
  for (int r = 0; r < R; ++r) hs[r][t] = fmaxf(acc[r], 0.f);
  __syncthreads();

  const int c = t & (OUTD - 1);
  const int rbase = (t >> 7) * (R / 2);
  float acc2[R / 2];
  {
    const float b = b1[c];
#pragma unroll
    for (int rr = 0; rr < R / 2; ++rr) acc2[rr] = b;
  }
  for (int k = 0; k < L; k += 4) {
    const float w0 = W1[(k + 0) * OUTD + c];
    const float w1 = W1[(k + 1) * OUTD + c];
    const float w2 = W1[(k + 2) * OUTD + c];
    const float w3 = W1[(k + 3) * OUTD + c];
#pragma unroll
    for (int rr = 0; rr < R / 2; ++rr) {
      const float4 h = *(const float4*)&hs[rbase + rr][k];
      acc2[rr] = fmaf(h.x, w0, acc2[rr]);
      acc2[rr] = fmaf(h.y, w1, acc2[rr]);
      acc2[rr] = fmaf(h.z, w2, acc2[rr]);
      acc2[rr] = fmaf(h.w, w3, acc2[rr]);
    }
  }
#pragma unroll
  for (int rr = 0; rr < R / 2; ++rr)
    out[(size_t)(n0 + rbase + rr) * OUTD + c] = acc2[rr];
}

// ---------------------------------------------------------------------------
extern "C" void kernel_launch(void* const* d_in, const int* in_sizes, int n_in,
                              void* d_out, int out_size, void* d_ws,
                              size_t ws_size, hipStream_t stream) {
  const float* node_feats = (const float*)d_in[0];
  const float* edge_feats = (const float*)d_in[1];
  const int* senders = (const int*)d_in[2];
  const int* receivers = (const int*)d_in[3];
  auto f = [&](int i) { return (const float*)d_in[i]; };

  float* nodes = (float*)d_ws;             // NN x L
  float* edges = nodes + (size_t)NN * L;   // NE x L
  float* agg = edges + (size_t)NE * L;     // NN x L

  embed_kernel<3, 16><<<NN / 16, 256, 0, stream>>>(
      node_feats, f(4), f(5), f(6), f(7), f(8), f(9), nodes);
  embed_kernel<4, 16><<<NE / 16, 256, 0, stream>>>(
      edge_feats, f(10), f(11), f(12), f(13), f(14), f(15), edges);

  for (int s = 0; s < SSTEPS; ++s) {
    hipMemsetAsync(agg, 0, (size_t)NN * L * sizeof(float), stream);
    edge_step_kernel<8><<<NE / 8, 256, 0, stream>>>(
        nodes, edges, agg, senders, receivers,
        f(16) + (size_t)s * 3 * L * 256, f(17) + (size_t)s * 256,
        f(18) + (size_t)s * 256 * L, f(19) + (size_t)s * L,
        f(20) + (size_t)s * L, f(21) + (size_t)s * L);
    node_step_kernel<8><<<NN / 8, 256, 0, stream>>>(
        nodes, agg, f(22) + (size_t)s * 2 * L * 256, f(23) + (size_t)s * 256,
        f(24) + (size_t)s * 256 * L, f(25) + (size_t)s * L,
        f(26) + (size_t)s * L, f(27) + (size_t)s * L);
  }

  decoder_kernel<8><<<NN / 8, 256, 0, stream>>>(nodes, f(28), f(29), f(30),
                                                f(31), (float*)d_out);
}

// Round 3
// 1883.869 us; speedup vs baseline: 3.8346x; 3.8346x over previous
//
#include <hip/hip_runtime.h>
#include <hip/hip_bf16.h>

#define NN 16384
#define NE 131072
#define L 256
#define SSTEPS 4
#define OUTD 128

typedef __attribute__((ext_vector_type(8))) short bf16x8;
typedef __attribute__((ext_vector_type(4))) float f32x4;

__device__ __forceinline__ short f2bs(float f) {
  unsigned u = __builtin_bit_cast(unsigned, f);
  u = (u + 0x7fffu + ((u >> 16) & 1u)) >> 16;
  return (short)u;
}
__device__ __forceinline__ float bs2f(short s) {
  unsigned u = ((unsigned)(unsigned short)s) << 16;
  return __builtin_bit_cast(float, u);
}
// load 8 consecutive f32 and round to bf16x8 (A-fragment)
__device__ __forceinline__ bf16x8 cvt8(const float* __restrict__ p) {
  float4 lo = *(const float4*)p;
  float4 hi = *(const float4*)(p + 4);
  bf16x8 r;
  r[0] = f2bs(lo.x); r[1] = f2bs(lo.y); r[2] = f2bs(lo.z); r[3] = f2bs(lo.w);
  r[4] = f2bs(hi.x); r[5] = f2bs(hi.y); r[6] = f2bs(hi.z); r[7] = f2bs(hi.w);
  return r;
}
__device__ __forceinline__ float wave_sum(float v) {
#pragma unroll
  for (int o = 32; o > 0; o >>= 1) v += __shfl_xor(v, o);
  return v;
}

// Store one 16x16 C-tile (f32x4 per lane) into swizzled bf16 LDS [64][256].
// C layout: row = mi*16 + (l>>4)*4 + i, col = nb + (l&15). Even lanes pack
// (own, lane+1 partner) into one b32 write. Swizzle: byte ^= (row&7)<<4.
__device__ __forceinline__ void store_tile(short* hs, int l, int mi, int nb,
                                           f32x4 v) {
  const int lm = l & 15, g = l >> 4;
#pragma unroll
  for (int i = 0; i < 4; ++i) {
    const float mine = v[i];
    const float part = __shfl_xor(mine, 1);
    if ((l & 1) == 0) {
      const int row = mi * 16 + g * 4 + i;
      const int col = nb + lm;  // even
      const unsigned pk = (unsigned)(unsigned short)f2bs(mine) |
                          ((unsigned)(unsigned short)f2bs(part) << 16);
      const int off = (row * 512 + col * 2) ^ ((row & 7) << 4);
      *(unsigned*)((char*)hs + off) = pk;
    }
  }
}

// GEMM from swizzled bf16 LDS h[64][256] times packed weights (K=256).
// Wave computes rows 0..63 x cols n0..n0+NT*16.
template <int NT>
__device__ __forceinline__ void gemm2_lds(const short* __restrict__ Wp,
                                          int Ncols, const short* hs, int n0,
                                          int l, f32x4 acc[4][NT]) {
  const int lm = l & 15, g = l >> 4;
#pragma unroll
  for (int kc = 0; kc < 8; ++kc) {
    bf16x8 a[4];
#pragma unroll
    for (int mi = 0; mi < 4; ++mi) {
      const int row = mi * 16 + lm;
      const int off = (row * 512 + kc * 64 + g * 16) ^ ((row & 7) << 4);
      a[mi] = *(const bf16x8*)((const char*)hs + off);
    }
#pragma unroll
    for (int ni = 0; ni < NT; ++ni) {
      const int n = n0 + ni * 16 + lm;
      bf16x8 b = *(const bf16x8*)(Wp + ((size_t)kc * Ncols + n) * 32 + g * 8);
#pragma unroll
      for (int mi = 0; mi < 4; ++mi)
        acc[mi][ni] =
            __builtin_amdgcn_mfma_f32_16x16x32_bf16(a[mi], b, acc[mi][ni], 0, 0, 0);
    }
  }
}

// Pack fp32 weight [K][N] (cnt stacked) into bf16 Wp[k/32][n][k%32].
__global__ void pack_w(const float* __restrict__ src, short* __restrict__ dst,
                       int K, int N, int cnt) {
  const size_t total = (size_t)K * N * cnt;
  for (size_t i = (size_t)blockIdx.x * blockDim.x + threadIdx.x; i < total;
       i += (size_t)gridDim.x * blockDim.x) {
    const size_t mat = i / ((size_t)K * N);
    const int rem = (int)(i - mat * (size_t)K * N);
    const int k = rem / N, n = rem - k * N;
    dst[mat * (size_t)K * N + ((size_t)(k >> 5) * N + n) * 32 + (k & 31)] =
        f2bs(src[i]);
  }
}

// ---------------------------------------------------------------------------
// Edge step: X=[edges|nodes[snd]|nodes[rcv]] (768) -> MFMA MLP -> LN ->
// edges += ne (fp32); atomicAdd agg[rcv] += ne.
// ---------------------------------------------------------------------------
__global__ __launch_bounds__(256) void edge_step_mfma(
    const float* __restrict__ nodes, float* __restrict__ edges,
    float* __restrict__ agg, const int* __restrict__ senders,
    const int* __restrict__ receivers, const short* __restrict__ W0p,
    const float* __restrict__ b0, const short* __restrict__ W1p,
    const float* __restrict__ b1, const float* __restrict__ ls,
    const float* __restrict__ lb) {
  __shared__ short hs[64 * 256];
  const int t = threadIdx.x, w = t >> 6, l = t & 63;
  const int lm = l & 15, g = l >> 4;
  const int e0 = blockIdx.x * 64;

  const float* baseA[3][4];
#pragma unroll
  for (int mi = 0; mi < 4; ++mi) {
    const int row = e0 + mi * 16 + lm;
    baseA[0][mi] = edges + (size_t)row * L;
    baseA[1][mi] = nodes + (size_t)senders[row] * L;
    baseA[2][mi] = nodes + (size_t)receivers[row] * L;
  }

  f32x4 acc[4][4] = {};
#pragma unroll
  for (int reg = 0; reg < 3; ++reg) {
#pragma unroll
    for (int kc8 = 0; kc8 < 8; ++kc8) {
      const int koff = kc8 * 32 + g * 8;
      bf16x8 a[4];
#pragma unroll
      for (int mi = 0; mi < 4; ++mi) a[mi] = cvt8(baseA[reg][mi] + koff);
      const int kcg = reg * 8 + kc8;
#pragma unroll
      for (int ni = 0; ni < 4; ++ni) {
        const int n = w * 64 + ni * 16 + lm;
        bf16x8 b = *(const bf16x8*)(W0p + ((size_t)kcg * L + n) * 32 + g * 8);
#pragma unroll
        for (int mi = 0; mi < 4; ++mi)
          acc[mi][ni] = __builtin_amdgcn_mfma_f32_16x16x32_bf16(a[mi], b,
                                                               acc[mi][ni],
                                                               0, 0, 0);
      }
    }
  }
  // bias + relu -> h in LDS
#pragma unroll
  for (int ni = 0; ni < 4; ++ni) {
    const float bia = b0[w * 64 + ni * 16 + lm];
#pragma unroll
    for (int mi = 0; mi < 4; ++mi) {
      f32x4 v = acc[mi][ni];
#pragma unroll
      for (int i = 0; i < 4; ++i) v[i] = fmaxf(v[i] + bia, 0.f);
      store_tile(hs, l, mi, w * 64 + ni * 16, v);
    }
  }
  __syncthreads();

  f32x4 acc2[4][4] = {};
  gemm2_lds<4>(W1p, L, hs, w * 64, l, acc2);
  __syncthreads();  // all h reads done; reuse hs for y
#pragma unroll
  for (int ni = 0; ni < 4; ++ni) {
    const float bia = b1[w * 64 + ni * 16 + lm];
#pragma unroll
    for (int mi = 0; mi < 4; ++mi) {
      f32x4 v = acc2[mi][ni];
#pragma unroll
      for (int i = 0; i < 4; ++i) v[i] += bia;
      store_tile(hs, l, mi, w * 64 + ni * 16, v);
    }
  }
  __syncthreads();

  // LN + residual + atomic scatter (wave w owns rows w*16..w*16+15)
  float ls4[4], lb4[4];
#pragma unroll
  for (int j = 0; j < 4; ++j) {
    ls4[j] = ls[l + 64 * j];
    lb4[j] = lb[l + 64 * j];
  }
#pragma unroll 4
  for (int rr = 0; rr < 16; ++rr) {
    const int r = w * 16 + rr;
    float v[4];
#pragma unroll
    for (int j = 0; j < 4; ++j) {
      const int off = (r * 512 + (l + 64 * j) * 2) ^ ((r & 7) << 4);
      v[j] = bs2f(*(const short*)((const char*)hs + off));
    }
    const float mu = wave_sum(v[0] + v[1] + v[2] + v[3]) * (1.f / 256.f);
    float sq = 0.f;
#pragma unroll
    for (int j = 0; j < 4; ++j) {
      v[j] -= mu;
      sq += v[j] * v[j];
    }
    const float rstd = rsqrtf(wave_sum(sq) * (1.f / 256.f) + 1e-6f);
    const size_t e = (size_t)(e0 + r);
    const int rc = receivers[e];
    float* er = edges + e * L;
    float* aggr = agg + (size_t)rc * L;
#pragma unroll
    for (int j = 0; j < 4; ++j) {
      const int c = l + 64 * j;
      const float ne = v[j] * rstd * ls4[j] + lb4[j];
      er[c] += ne;
      atomicAdd(aggr + c, ne);
    }
  }
}

// ---------------------------------------------------------------------------
// Node step: X=[nodes|agg] (512) -> MFMA MLP -> LN -> nodes += ne
// ---------------------------------------------------------------------------
__global__ __launch_bounds__(256) void node_step_mfma(
    float* __restrict__ nodes, const float* __restrict__ agg,
    const short* __restrict__ W0p, const float* __restrict__ b0,
    const short* __restrict__ W1p, const float* __restrict__ b1,
    const float* __restrict__ ls, const float* __restrict__ lb) {
  __shared__ short hs[64 * 256];
  const int t = threadIdx.x, w = t >> 6, l = t & 63;
  const int lm = l & 15, g = l >> 4;
  const int n0 = blockIdx.x * 64;

  const float* baseA[2][4];
#pragma unroll
  for (int mi = 0; mi < 4; ++mi) {
    const size_t row = n0 + mi * 16 + lm;
    baseA[0][mi] = nodes + row * L;
    baseA[1][mi] = agg + row * L;
  }

  f32x4 acc[4][4] = {};
#pragma unroll
  for (int reg = 0; reg < 2; ++reg) {
#pragma unroll
    for (int kc8 = 0; kc8 < 8; ++kc8) {
      const int koff = kc8 * 32 + g * 8;
      bf16x8 a[4];
#pragma unroll
      for (int mi = 0; mi < 4; ++mi) a[mi] = cvt8(baseA[reg][mi] + koff);
      const int kcg = reg * 8 + kc8;
#pragma unroll
      for (int ni = 0; ni < 4; ++ni) {
        const int n = w * 64 + ni * 16 + lm;
        bf16x8 b = *(const bf16x8*)(W0p + ((size_t)kcg * L + n) * 32 + g * 8);
#pragma unroll
        for (int mi = 0; mi < 4; ++mi)
          acc[mi][ni] = __builtin_amdgcn_mfma_f32_16x16x32_bf16(a[mi], b,
                                                               acc[mi][ni],
                                                               0, 0, 0);
      }
    }
  }
#pragma unroll
  for (int ni = 0; ni < 4; ++ni) {
    const float bia = b0[w * 64 + ni * 16 + lm];
#pragma unroll
    for (int mi = 0; mi < 4; ++mi) {
      f32x4 v = acc[mi][ni];
#pragma unroll
      for (int i = 0; i < 4; ++i) v[i] = fmaxf(v[i] + bia, 0.f);
      store_tile(hs, l, mi, w * 64 + ni * 16, v);
    }
  }
  __syncthreads();

  f32x4 acc2[4][4] = {};
  gemm2_lds<4>(W1p, L, hs, w * 64, l, acc2);
  __syncthreads();
#pragma unroll
  for (int ni = 0; ni < 4; ++ni) {
    const float bia = b1[w * 64 + ni * 16 + lm];
#pragma unroll
    for (int mi = 0; mi < 4; ++mi) {
      f32x4 v = acc2[mi][ni];
#pragma unroll
      for (int i = 0; i < 4; ++i) v[i] += bia;
      store_tile(hs, l, mi, w * 64 + ni * 16, v);
    }
  }
  __syncthreads();

  float ls4[4], lb4[4];
#pragma unroll
  for (int j = 0; j < 4; ++j) {
    ls4[j] = ls[l + 64 * j];
    lb4[j] = lb[l + 64 * j];
  }
#pragma unroll 4
  for (int rr = 0; rr < 16; ++rr) {
    const int r = w * 16 + rr;
    float v[4];
#pragma unroll
    for (int j = 0; j < 4; ++j) {
      const int off = (r * 512 + (l + 64 * j) * 2) ^ ((r & 7) << 4);
      v[j] = bs2f(*(const short*)((const char*)hs + off));
    }
    const float mu = wave_sum(v[0] + v[1] + v[2] + v[3]) * (1.f / 256.f);
    float sq = 0.f;
#pragma unroll
    for (int j = 0; j < 4; ++j) {
      v[j] -= mu;
      sq += v[j] * v[j];
    }
    const float rstd = rsqrtf(wave_sum(sq) * (1.f / 256.f) + 1e-6f);
    float* nr = nodes + (size_t)(n0 + r) * L;
#pragma unroll
    for (int j = 0; j < 4; ++j) {
      const int c = l + 64 * j;
      const float ne = v[j] * rstd * ls4[j] + lb4[j];
      nr[c] += ne;
    }
  }
}

// ---------------------------------------------------------------------------
// Embedder: layer1 (K1->256, VALU) -> h in LDS -> MFMA layer2 -> LN -> dst
// ---------------------------------------------------------------------------
template <int K1>
__global__ __launch_bounds__(256) void embed_mfma(
    const float* __restrict__ x, const float* __restrict__ W0,
    const float* __restrict__ b0, const short* __restrict__ W1p,
    const float* __restrict__ b1, const float* __restrict__ ls,
    const float* __restrict__ lb, float* __restrict__ dst) {
  __shared__ short hs[64 * 256];
  __shared__ float xs[64][K1];
  const int t = threadIdx.x, w = t >> 6, l = t & 63;
  const int r0 = blockIdx.x * 64;

  if (t < 64 * K1) xs[t / K1][t % K1] = x[(size_t)r0 * K1 + t];
  __syncthreads();

  float wc[K1];
#pragma unroll
  for (int k = 0; k < K1; ++k) wc[k] = W0[k * L + t];
  const float bb = b0[t];
  for (int r = 0; r < 64; ++r) {
    float h = bb;
#pragma unroll
    for (int k = 0; k < K1; ++k) h = fmaf(xs[r][k], wc[k], h);
    h = fmaxf(h, 0.f);
    const int off = (r * 512 + t * 2) ^ ((r & 7) << 4);
    *(short*)((char*)hs + off) = f2bs(h);
  }
  __syncthreads();

  const int lm = l & 15;
  f32x4 acc2[4][4] = {};
  gemm2_lds<4>(W1p, L, hs, w * 64, l, acc2);
  __syncthreads();
#pragma unroll
  for (int ni = 0; ni < 4; ++ni) {
    const float bia = b1[w * 64 + ni * 16 + lm];
#pragma unroll
    for (int mi = 0; mi < 4; ++mi) {
      f32x4 v = acc2[mi][ni];
#pragma unroll
      for (int i = 0; i < 4; ++i) v[i] += bia;
      store_tile(hs, l, mi, w * 64 + ni * 16, v);
    }
  }
  __syncthreads();

  float ls4[4], lb4[4];
#pragma unroll
  for (int j = 0; j < 4; ++j) {
    ls4[j] = ls[l + 64 * j];
    lb4[j] = lb[l + 64 * j];
  }
#pragma unroll 4
  for (int rr = 0; rr < 16; ++rr) {
    const int r = w * 16 + rr;
    float v[4];
#pragma unroll
    for (int j = 0; j < 4; ++j) {
      const int off = (r * 512 + (l + 64 * j) * 2) ^ ((r & 7) << 4);
      v[j] = bs2f(*(const short*)((const char*)hs + off));
    }
    const float mu = wave_sum(v[0] + v[1] + v[2] + v[3]) * (1.f / 256.f);
    float sq = 0.f;
#pragma unroll
    for (int j = 0; j < 4; ++j) {
      v[j] -= mu;
      sq += v[j] * v[j];
    }
    const float rstd = rsqrtf(wave_sum(sq) * (1.f / 256.f) + 1e-6f);
    float* dr = dst + (size_t)(r0 + r) * L;
#pragma unroll
    for (int j = 0; j < 4; ++j) {
      const int c = l + 64 * j;
      dr[c] = v[j] * rstd * ls4[j] + lb4[j];
    }
  }
}

// ---------------------------------------------------------------------------
// Decoder: nodes (256) -> MFMA 256 relu -> MFMA 128 -> out (fp32, no LN)
// ---------------------------------------------------------------------------
__global__ __launch_bounds__(256) void decoder_mfma(
    const float* __restrict__ nodes, const short* __restrict__ W0p,
    const float* __restrict__ b0, const short* __restrict__ W1p,
    const float* __restrict__ b1, float* __restrict__ out) {
  __shared__ short hs[64 * 256];
  const int t = threadIdx.x, w = t >> 6, l = t & 63;
  const int lm = l & 15, g = l >> 4;
  const int n0 = blockIdx.x * 64;

  const float* baseA[4];
#pragma unroll
  for (int mi = 0; mi < 4; ++mi)
    baseA[mi] = nodes + (size_t)(n0 + mi * 16 + lm) * L;

  f32x4 acc[4][4] = {};
#pragma unroll
  for (int kc = 0; kc < 8; ++kc) {
    const int koff = kc * 32 + g * 8;
    bf16x8 a[4];
#pragma unroll
    for (int mi = 0; mi < 4; ++mi) a[mi] = cvt8(baseA[mi] + koff);
#pragma unroll
    for (int ni = 0; ni < 4; ++ni) {
      const int n = w * 64 + ni * 16 + lm;
      bf16x8 b = *(const bf16x8*)(W0p + ((size_t)kc * L + n) * 32 + g * 8);
#pragma unroll
      for (int mi = 0; mi < 4; ++mi)
        acc[mi][ni] = __builtin_amdgcn_mfma_f32_16x16x32_bf16(a[mi], b,
                                                             acc[mi][ni],
                                                             0, 0, 0);
    }
  }
#pragma unroll
  for (int ni = 0; ni < 4; ++ni) {
    const float bia = b0[w * 64 + ni * 16 + lm];
#pragma unroll
    for (int mi = 0; mi < 4; ++mi) {
      f32x4 v = acc[mi][ni];
#pragma unroll
      for (int i = 0; i < 4; ++i) v[i] = fmaxf(v[i] + bia, 0.f);
      store_tile(hs, l, mi, w * 64 + ni * 16, v);
    }
  }
  __syncthreads();

  f32x4 acc2[4][2] = {};
  gemm2_lds<2>(W1p, OUTD, hs, w * 32, l, acc2);

  float b14[2];
#pragma unroll
  for (int ni = 0; ni < 2; ++ni) b14[ni] = b1[w * 32 + ni * 16 + lm];
#pragma unroll
  for (int mi = 0; mi < 4; ++mi)
#pragma unroll
    for (int ni = 0; ni < 2; ++ni)
#pragma unroll
      for (int i = 0; i < 4; ++i) {
        const int row = n0 + mi * 16 + g * 4 + i;
        const int col = w * 32 + ni * 16 + lm;
        out[(size_t)row * OUTD + col] = acc2[mi][ni][i] + b14[ni];
      }
}

// ---------------------------------------------------------------------------
extern "C" void kernel_launch(void* const* d_in, const int* in_sizes, int n_in,
                              void* d_out, int out_size, void* d_ws,
                              size_t ws_size, hipStream_t stream) {
  const float* node_feats = (const float*)d_in[0];
  const float* edge_feats = (const float*)d_in[1];
  const int* senders = (const int*)d_in[2];
  const int* receivers = (const int*)d_in[3];
  auto f = [&](int i) { return (const float*)d_in[i]; };

  float* nodes = (float*)d_ws;             // NN x L f32
  float* edges = nodes + (size_t)NN * L;   // NE x L f32
  float* agg = edges + (size_t)NE * L;     // NN x L f32
  short* en_W1p = (short*)(agg + (size_t)NN * L);
  short* ee_W1p = en_W1p + 65536;
  short* pe_W0p = ee_W1p + 65536;          // 4 x 768 x 256
  short* pe_W1p = pe_W0p + 4 * 768 * 256;  // 4 x 256 x 256
  short* pn_W0p = pe_W1p + 4 * 65536;      // 4 x 512 x 256
  short* pn_W1p = pn_W0p + 4 * 512 * 256;  // 4 x 256 x 256
  short* dn_W0p = pn_W1p + 4 * 65536;      // 256 x 256
  short* dn_W1p = dn_W0p + 65536;          // 256 x 128

  pack_w<<<256, 256, 0, stream>>>(f(6), en_W1p, 256, 256, 1);
  pack_w<<<256, 256, 0, stream>>>(f(12), ee_W1p, 256, 256, 1);
  pack_w<<<1024, 256, 0, stream>>>(f(16), pe_W0p, 768, 256, 4);
  pack_w<<<512, 256, 0, stream>>>(f(18), pe_W1p, 256, 256, 4);
  pack_w<<<1024, 256, 0, stream>>>(f(22), pn_W0p, 512, 256, 4);
  pack_w<<<512, 256, 0, stream>>>(f(24), pn_W1p, 256, 256, 4);
  pack_w<<<256, 256, 0, stream>>>(f(28), dn_W0p, 256, 256, 1);
  pack_w<<<128, 256, 0, stream>>>(f(30), dn_W1p, 256, 128, 1);

  embed_mfma<3><<<NN / 64, 256, 0, stream>>>(node_feats, f(4), f(5), en_W1p,
                                             f(7), f(8), f(9), nodes);
  embed_mfma<4><<<NE / 64, 256, 0, stream>>>(edge_feats, f(10), f(11), ee_W1p,
                                             f(13), f(14), f(15), edges);

  for (int s = 0; s < SSTEPS; ++s) {
    hipMemsetAsync(agg, 0, (size_t)NN * L * sizeof(float), stream);
    edge_step_mfma<<<NE / 64, 256, 0, stream>>>(
        nodes, edges, agg, senders, receivers,
        pe_W0p + (size_t)s * 768 * 256, f(17) + (size_t)s * 256,
        pe_W1p + (size_t)s * 65536, f(19) + (size_t)s * 256,
        f(20) + (size_t)s * 256, f(21) + (size_t)s * 256);
    node_step_mfma<<<NN / 64, 256, 0, stream>>>(
        nodes, agg, pn_W0p + (size_t)s * 512 * 256, f(23) + (size_t)s * 256,
        pn_W1p + (size_t)s * 65536, f(25) + (size_t)s * 256,
        f(26) + (size_t)s * 256, f(27) + (size_t)s * 256);
  }

  decoder_mfma<<<NN / 64, 256, 0, stream>>>(nodes, dn_W0p, f(29), dn_W1p,
                                            f(31), (float*)d_out);
}

// Round 4
// 1500.249 us; speedup vs baseline: 4.8151x; 1.2557x over previous
//
#include <hip/hip_runtime.h>
#include <hip/hip_bf16.h>

#define NN 16384
#define NE 131072
#define L 256
#define SSTEPS 4
#define OUTD 128

typedef __attribute__((ext_vector_type(8))) short bf16x8;
typedef __attribute__((ext_vector_type(4))) float f32x4;

__device__ __forceinline__ short f2bs(float f) {
  unsigned u = __builtin_bit_cast(unsigned, f);
  u = (u + 0x7fffu + ((u >> 16) & 1u)) >> 16;
  return (short)u;
}
__device__ __forceinline__ float bs2f(short s) {
  unsigned u = ((unsigned)(unsigned short)s) << 16;
  return __builtin_bit_cast(float, u);
}
__device__ __forceinline__ bf16x8 pack8(float4 lo, float4 hi) {
  bf16x8 r;
  r[0] = f2bs(lo.x); r[1] = f2bs(lo.y); r[2] = f2bs(lo.z); r[3] = f2bs(lo.w);
  r[4] = f2bs(hi.x); r[5] = f2bs(hi.y); r[6] = f2bs(hi.z); r[7] = f2bs(hi.w);
  return r;
}
__device__ __forceinline__ bf16x8 cvt8(const float* __restrict__ p) {
  return pack8(*(const float4*)p, *(const float4*)(p + 4));
}
__device__ __forceinline__ float wave_sum(float v) {
#pragma unroll
  for (int o = 32; o > 0; o >>= 1) v += __shfl_xor(v, o);
  return v;
}

// Store one 16x16 C-tile (f32x4 per lane) into swizzled bf16 LDS [64][256]
// (row stride 512B). byte ^= (row&7)<<4.
__device__ __forceinline__ void store_tile(short* hs, int l, int mi, int nb,
                                           f32x4 v) {
  const int lm = l & 15, g = l >> 4;
#pragma unroll
  for (int i = 0; i < 4; ++i) {
    const float mine = v[i];
    const float part = __shfl_xor(mine, 1);
    if ((l & 1) == 0) {
      const int row = mi * 16 + g * 4 + i;
      const int col = nb + lm;  // even
      const unsigned pk = (unsigned)(unsigned short)f2bs(mine) |
                          ((unsigned)(unsigned short)f2bs(part) << 16);
      const int off = (row * 512 + col * 2) ^ ((row & 7) << 4);
      *(unsigned*)((char*)hs + off) = pk;
    }
  }
}

// GEMM from swizzled bf16 LDS h[64][256] (512B stride) x packed W (K=256).
template <int NT>
__device__ __forceinline__ void gemm2_lds(const short* __restrict__ Wp,
                                          int Ncols, const short* hs, int n0,
                                          int l, f32x4 acc[4][NT]) {
  const int lm = l & 15, g = l >> 4;
#pragma unroll
  for (int kc = 0; kc < 8; ++kc) {
    bf16x8 a[4];
#pragma unroll
    for (int mi = 0; mi < 4; ++mi) {
      const int row = mi * 16 + lm;
      const int off = (row * 512 + kc * 64 + g * 16) ^ ((row & 7) << 4);
      a[mi] = *(const bf16x8*)((const char*)hs + off);
    }
#pragma unroll
    for (int ni = 0; ni < NT; ++ni) {
      const int n = n0 + ni * 16 + lm;
      bf16x8 b = *(const bf16x8*)(Wp + ((size_t)kc * Ncols + n) * 32 + g * 8);
#pragma unroll
      for (int mi = 0; mi < 4; ++mi)
        acc[mi][ni] =
            __builtin_amdgcn_mfma_f32_16x16x32_bf16(a[mi], b, acc[mi][ni], 0, 0, 0);
    }
  }
}

// Pack fp32 weight [K][N] (cnt stacked) into bf16 Wp[k/32][n][k%32].
__global__ void pack_w(const float* __restrict__ src, short* __restrict__ dst,
                       int K, int N, int cnt) {
  const size_t total = (size_t)K * N * cnt;
  for (size_t i = (size_t)blockIdx.x * blockDim.x + threadIdx.x; i < total;
       i += (size_t)gridDim.x * blockDim.x) {
    const size_t mat = i / ((size_t)K * N);
    const int rem = (int)(i - mat * (size_t)K * N);
    const int k = rem / N, n = rem - k * N;
    dst[mat * (size_t)K * N + ((size_t)(k >> 5) * N + n) * 32 + (k & 31)] =
        f2bs(src[i]);
  }
}

// Layer-1 MFMA over one staged 128-K chunk in As (row stride 256B, swizzled).
__device__ __forceinline__ void mfma_chunk(const short* __restrict__ As,
                                           const short* __restrict__ W0p,
                                           int kcg_base, int w, int l,
                                           f32x4 acc[4][4]) {
  const int lm = l & 15, g = l >> 4;
#pragma unroll
  for (int kc = 0; kc < 4; ++kc) {
    bf16x8 a[4];
#pragma unroll
    for (int mi = 0; mi < 4; ++mi) {
      const int row = mi * 16 + lm;
      const int off = (row * 256 + kc * 64 + g * 16) ^ ((row & 7) << 4);
      a[mi] = *(const bf16x8*)((const char*)As + off);
    }
#pragma unroll
    for (int ni = 0; ni < 4; ++ni) {
      const int n = w * 64 + ni * 16 + lm;
      bf16x8 b =
          *(const bf16x8*)(W0p + ((size_t)(kcg_base + kc) * L + n) * 32 + g * 8);
#pragma unroll
      for (int mi = 0; mi < 4; ++mi)
        acc[mi][ni] =
            __builtin_amdgcn_mfma_f32_16x16x32_bf16(a[mi], b, acc[mi][ni], 0, 0, 0);
    }
  }
}

// ---------------------------------------------------------------------------
// Edge step: X=[edges|nodes[snd]|nodes[rcv]] (768) -> MFMA MLP -> LN ->
// edges += ne; atomicAdd agg[rcv] += ne. LDS-staged double-buffered layer 1.
// ---------------------------------------------------------------------------
__global__ __launch_bounds__(256) void edge_step_mfma(
    const float* __restrict__ nodes, float* __restrict__ edges,
    float* __restrict__ agg, const int* __restrict__ senders,
    const int* __restrict__ receivers, const short* __restrict__ W0p,
    const float* __restrict__ b0, const short* __restrict__ W1p,
    const float* __restrict__ b1, const float* __restrict__ ls,
    const float* __restrict__ lb) {
  __shared__ short smem[64 * 256];  // 32KB: As[2][64][128] then h/y[64][256]
  __shared__ int sn_s[64], rc_s[64];
  const int t = threadIdx.x, w = t >> 6, l = t & 63;
  const int lm = l & 15, g = l >> 4;
  const int tr = t >> 4, seg = t & 15;
  const int e0 = blockIdx.x * 64;
  short* As0 = smem;
  short* As1 = smem + 8192;

  if (t < 64) sn_s[t] = senders[e0 + t];
  else if (t < 128) rc_s[t - 64] = receivers[e0 + t - 64];

  float4 o[4][2];
  // prologue: load + write chunk 0 (edges, k 0..127)
#pragma unroll
  for (int p = 0; p < 4; ++p) {
    const float* pp = edges + (size_t)(e0 + p * 16 + tr) * L + seg * 8;
    o[p][0] = *(const float4*)pp;
    o[p][1] = *(const float4*)(pp + 4);
  }
#pragma unroll
  for (int p = 0; p < 4; ++p) {
    const int row = p * 16 + tr;
    const int off = (row * 256 + seg * 16) ^ ((row & 7) << 4);
    *(bf16x8*)((char*)As0 + off) = pack8(o[p][0], o[p][1]);
  }
  __syncthreads();

  f32x4 acc[4][4] = {};
#pragma unroll
  for (int c = 0; c < 6; ++c) {
    if (c + 1 < 6) {  // issue next chunk's global loads (hide under MFMA)
      const int cn = c + 1;
      const float* src;
      const int* ridx = nullptr;
      int cb, rb = 0;
      if (cn < 2) { src = edges; cb = cn * 128; rb = e0; }
      else if (cn < 4) { src = nodes; cb = (cn - 2) * 128; ridx = sn_s; }
      else { src = nodes; cb = (cn - 4) * 128; ridx = rc_s; }
#pragma unroll
      for (int p = 0; p < 4; ++p) {
        const int row = p * 16 + tr;
        const size_t gr = ridx ? (size_t)ridx[row] : (size_t)(rb + row);
        const float* pp = src + gr * L + cb + seg * 8;
        o[p][0] = *(const float4*)pp;
        o[p][1] = *(const float4*)(pp + 4);
      }
    }
    mfma_chunk((c & 1) ? As1 : As0, W0p, c * 4, w, l, acc);
    if (c + 1 < 6) {
      short* dbuf = (c & 1) ? As0 : As1;
#pragma unroll
      for (int p = 0; p < 4; ++p) {
        const int row = p * 16 + tr;
        const int off = (row * 256 + seg * 16) ^ ((row & 7) << 4);
        *(bf16x8*)((char*)dbuf + off) = pack8(o[p][0], o[p][1]);
      }
    }
    __syncthreads();
  }

  // bias + relu -> h in smem (now viewed as [64][256], 512B stride)
#pragma unroll
  for (int ni = 0; ni < 4; ++ni) {
    const float bia = b0[w * 64 + ni * 16 + lm];
#pragma unroll
    for (int mi = 0; mi < 4; ++mi) {
      f32x4 v = acc[mi][ni];
#pragma unroll
      for (int i = 0; i < 4; ++i) v[i] = fmaxf(v[i] + bia, 0.f);
      store_tile(smem, l, mi, w * 64 + ni * 16, v);
    }
  }
  __syncthreads();

  f32x4 acc2[4][4] = {};
  gemm2_lds<4>(W1p, L, smem, w * 64, l, acc2);
  __syncthreads();
#pragma unroll
  for (int ni = 0; ni < 4; ++ni) {
    const float bia = b1[w * 64 + ni * 16 + lm];
#pragma unroll
    for (int mi = 0; mi < 4; ++mi) {
      f32x4 v = acc2[mi][ni];
#pragma unroll
      for (int i = 0; i < 4; ++i) v[i] += bia;
      store_tile(smem, l, mi, w * 64 + ni * 16, v);
    }
  }
  __syncthreads();

  float ls4[4], lb4[4];
#pragma unroll
  for (int j = 0; j < 4; ++j) {
    ls4[j] = ls[l + 64 * j];
    lb4[j] = lb[l + 64 * j];
  }
#pragma unroll 4
  for (int rr = 0; rr < 16; ++rr) {
    const int r = w * 16 + rr;
    float v[4];
#pragma unroll
    for (int j = 0; j < 4; ++j) {
      const int off = (r * 512 + (l + 64 * j) * 2) ^ ((r & 7) << 4);
      v[j] = bs2f(*(const short*)((const char*)smem + off));
    }
    const float mu = wave_sum(v[0] + v[1] + v[2] + v[3]) * (1.f / 256.f);
    float sq = 0.f;
#pragma unroll
    for (int j = 0; j < 4; ++j) {
      v[j] -= mu;
      sq += v[j] * v[j];
    }
    const float rstd = rsqrtf(wave_sum(sq) * (1.f / 256.f) + 1e-6f);
    const size_t e = (size_t)(e0 + r);
    const int rc = rc_s[r];
    float* er = edges + e * L;
    float* aggr = agg + (size_t)rc * L;
#pragma unroll
    for (int j = 0; j < 4; ++j) {
      const int c = l + 64 * j;
      const float ne = v[j] * rstd * ls4[j] + lb4[j];
      er[c] += ne;
      atomicAdd(aggr + c, ne);
    }
  }
}

// ---------------------------------------------------------------------------
// Node step: X=[nodes|agg] (512) -> MFMA MLP -> LN -> nodes += ne
// ---------------------------------------------------------------------------
__global__ __launch_bounds__(256) void node_step_mfma(
    float* __restrict__ nodes, const float* __restrict__ agg,
    const short* __restrict__ W0p, const float* __restrict__ b0,
    const short* __restrict__ W1p, const float* __restrict__ b1,
    const float* __restrict__ ls, const float* __restrict__ lb) {
  __shared__ short smem[64 * 256];
  const int t = threadIdx.x, w = t >> 6, l = t & 63;
  const int lm = l & 15, g = l >> 4;
  const int tr = t >> 4, seg = t & 15;
  const int n0 = blockIdx.x * 64;
  short* As0 = smem;
  short* As1 = smem + 8192;

  float4 o[4][2];
#pragma unroll
  for (int p = 0; p < 4; ++p) {
    const float* pp = nodes + (size_t)(n0 + p * 16 + tr) * L + seg * 8;
    o[p][0] = *(const float4*)pp;
    o[p][1] = *(const float4*)(pp + 4);
  }
#pragma unroll
  for (int p = 0; p < 4; ++p) {
    const int row = p * 16 + tr;
    const int off = (row * 256 + seg * 16) ^ ((row & 7) << 4);
    *(bf16x8*)((char*)As0 + off) = pack8(o[p][0], o[p][1]);
  }
  __syncthreads();

  f32x4 acc[4][4] = {};
#pragma unroll
  for (int c = 0; c < 4; ++c) {
    if (c + 1 < 4) {
      const int cn = c + 1;
      const float* src = (cn < 2) ? nodes : agg;
      const int cb = (cn & 1) * 128;
#pragma unroll
      for (int p = 0; p < 4; ++p) {
        const float* pp = src + (size_t)(n0 + p * 16 + tr) * L + cb + seg * 8;
        o[p][0] = *(const float4*)pp;
        o[p][1] = *(const float4*)(pp + 4);
      }
    }
    mfma_chunk((c & 1) ? As1 : As0, W0p, c * 4, w, l, acc);
    if (c + 1 < 4) {
      short* dbuf = (c & 1) ? As0 : As1;
#pragma unroll
      for (int p = 0; p < 4; ++p) {
        const int row = p * 16 + tr;
        const int off = (row * 256 + seg * 16) ^ ((row & 7) << 4);
        *(bf16x8*)((char*)dbuf + off) = pack8(o[p][0], o[p][1]);
      }
    }
    __syncthreads();
  }

#pragma unroll
  for (int ni = 0; ni < 4; ++ni) {
    const float bia = b0[w * 64 + ni * 16 + lm];
#pragma unroll
    for (int mi = 0; mi < 4; ++mi) {
      f32x4 v = acc[mi][ni];
#pragma unroll
      for (int i = 0; i < 4; ++i) v[i] = fmaxf(v[i] + bia, 0.f);
      store_tile(smem, l, mi, w * 64 + ni * 16, v);
    }
  }
  __syncthreads();

  f32x4 acc2[4][4] = {};
  gemm2_lds<4>(W1p, L, smem, w * 64, l, acc2);
  __syncthreads();
#pragma unroll
  for (int ni = 0; ni < 4; ++ni) {
    const float bia = b1[w * 64 + ni * 16 + lm];
#pragma unroll
    for (int mi = 0; mi < 4; ++mi) {
      f32x4 v = acc2[mi][ni];
#pragma unroll
      for (int i = 0; i < 4; ++i) v[i] += bia;
      store_tile(smem, l, mi, w * 64 + ni * 16, v);
    }
  }
  __syncthreads();

  float ls4[4], lb4[4];
#pragma unroll
  for (int j = 0; j < 4; ++j) {
    ls4[j] = ls[l + 64 * j];
    lb4[j] = lb[l + 64 * j];
  }
#pragma unroll 4
  for (int rr = 0; rr < 16; ++rr) {
    const int r = w * 16 + rr;
    float v[4];
#pragma unroll
    for (int j = 0; j < 4; ++j) {
      const int off = (r * 512 + (l + 64 * j) * 2) ^ ((r & 7) << 4);
      v[j] = bs2f(*(const short*)((const char*)smem + off));
    }
    const float mu = wave_sum(v[0] + v[1] + v[2] + v[3]) * (1.f / 256.f);
    float sq = 0.f;
#pragma unroll
    for (int j = 0; j < 4; ++j) {
      v[j] -= mu;
      sq += v[j] * v[j];
    }
    const float rstd = rsqrtf(wave_sum(sq) * (1.f / 256.f) + 1e-6f);
    float* nr = nodes + (size_t)(n0 + r) * L;
#pragma unroll
    for (int j = 0; j < 4; ++j) {
      const int c = l + 64 * j;
      const float ne = v[j] * rstd * ls4[j] + lb4[j];
      nr[c] += ne;
    }
  }
}

// ---------------------------------------------------------------------------
// Embedder: layer1 (K1->256, VALU) -> h in LDS -> MFMA layer2 -> LN -> dst
// ---------------------------------------------------------------------------
template <int K1>
__global__ __launch_bounds__(256) void embed_mfma(
    const float* __restrict__ x, const float* __restrict__ W0,
    const float* __restrict__ b0, const short* __restrict__ W1p,
    const float* __restrict__ b1, const float* __restrict__ ls,
    const float* __restrict__ lb, float* __restrict__ dst) {
  __shared__ short hs[64 * 256];
  __shared__ float xs[64][K1];
  const int t = threadIdx.x, w = t >> 6, l = t & 63;
  const int r0 = blockIdx.x * 64;

  if (t < 64 * K1) xs[t / K1][t % K1] = x[(size_t)r0 * K1 + t];
  __syncthreads();

  float wc[K1];
#pragma unroll
  for (int k = 0; k < K1; ++k) wc[k] = W0[k * L + t];
  const float bb = b0[t];
  for (int r = 0; r < 64; ++r) {
    float h = bb;
#pragma unroll
    for (int k = 0; k < K1; ++k) h = fmaf(xs[r][k], wc[k], h);
    h = fmaxf(h, 0.f);
    const int off = (r * 512 + t * 2) ^ ((r & 7) << 4);
    *(short*)((char*)hs + off) = f2bs(h);
  }
  __syncthreads();

  const int lm = l & 15;
  f32x4 acc2[4][4] = {};
  gemm2_lds<4>(W1p, L, hs, w * 64, l, acc2);
  __syncthreads();
#pragma unroll
  for (int ni = 0; ni < 4; ++ni) {
    const float bia = b1[w * 64 + ni * 16 + lm];
#pragma unroll
    for (int mi = 0; mi < 4; ++mi) {
      f32x4 v = acc2[mi][ni];
#pragma unroll
      for (int i = 0; i < 4; ++i) v[i] += bia;
      store_tile(hs, l, mi, w * 64 + ni * 16, v);
    }
  }
  __syncthreads();

  float ls4[4], lb4[4];
#pragma unroll
  for (int j = 0; j < 4; ++j) {
    ls4[j] = ls[l + 64 * j];
    lb4[j] = lb[l + 64 * j];
  }
#pragma unroll 4
  for (int rr = 0; rr < 16; ++rr) {
    const int r = w * 16 + rr;
    float v[4];
#pragma unroll
    for (int j = 0; j < 4; ++j) {
      const int off = (r * 512 + (l + 64 * j) * 2) ^ ((r & 7) << 4);
      v[j] = bs2f(*(const short*)((const char*)hs + off));
    }
    const float mu = wave_sum(v[0] + v[1] + v[2] + v[3]) * (1.f / 256.f);
    float sq = 0.f;
#pragma unroll
    for (int j = 0; j < 4; ++j) {
      v[j] -= mu;
      sq += v[j] * v[j];
    }
    const float rstd = rsqrtf(wave_sum(sq) * (1.f / 256.f) + 1e-6f);
    float* dr = dst + (size_t)(r0 + r) * L;
#pragma unroll
    for (int j = 0; j < 4; ++j) {
      const int c = l + 64 * j;
      dr[c] = v[j] * rstd * ls4[j] + lb4[j];
    }
  }
}

// ---------------------------------------------------------------------------
// Decoder: nodes (256) -> MFMA 256 relu -> MFMA 128 -> out (fp32, no LN)
// ---------------------------------------------------------------------------
__global__ __launch_bounds__(256) void decoder_mfma(
    const float* __restrict__ nodes, const short* __restrict__ W0p,
    const float* __restrict__ b0, const short* __restrict__ W1p,
    const float* __restrict__ b1, float* __restrict__ out) {
  __shared__ short hs[64 * 256];
  const int t = threadIdx.x, w = t >> 6, l = t & 63;
  const int lm = l & 15, g = l >> 4;
  const int n0 = blockIdx.x * 64;

  const float* baseA[4];
#pragma unroll
  for (int mi = 0; mi < 4; ++mi)
    baseA[mi] = nodes + (size_t)(n0 + mi * 16 + lm) * L;

  f32x4 acc[4][4] = {};
#pragma unroll
  for (int kc = 0; kc < 8; ++kc) {
    const int koff = kc * 32 + g * 8;
    bf16x8 a[4];
#pragma unroll
    for (int mi = 0; mi < 4; ++mi) a[mi] = cvt8(baseA[mi] + koff);
#pragma unroll
    for (int ni = 0; ni < 4; ++ni) {
      const int n = w * 64 + ni * 16 + lm;
      bf16x8 b = *(const bf16x8*)(W0p + ((size_t)kc * L + n) * 32 + g * 8);
#pragma unroll
      for (int mi = 0; mi < 4; ++mi)
        acc[mi][ni] = __builtin_amdgcn_mfma_f32_16x16x32_bf16(a[mi], b,
                                                             acc[mi][ni],
                                                             0, 0, 0);
    }
  }
#pragma unroll
  for (int ni = 0; ni < 4; ++ni) {
    const float bia = b0[w * 64 + ni * 16 + lm];
#pragma unroll
    for (int mi = 0; mi < 4; ++mi) {
      f32x4 v = acc[mi][ni];
#pragma unroll
      for (int i = 0; i < 4; ++i) v[i] = fmaxf(v[i] + bia, 0.f);
      store_tile(hs, l, mi, w * 64 + ni * 16, v);
    }
  }
  __syncthreads();

  f32x4 acc2[4][2] = {};
  gemm2_lds<2>(W1p, OUTD, hs, w * 32, l, acc2);

  float b14[2];
#pragma unroll
  for (int ni = 0; ni < 2; ++ni) b14[ni] = b1[w * 32 + ni * 16 + lm];
#pragma unroll
  for (int mi = 0; mi < 4; ++mi)
#pragma unroll
    for (int ni = 0; ni < 2; ++ni)
#pragma unroll
      for (int i = 0; i < 4; ++i) {
        const int row = n0 + mi * 16 + g * 4 + i;
        const int col = w * 32 + ni * 16 + lm;
        out[(size_t)row * OUTD + col] = acc2[mi][ni][i] + b14[ni];
      }
}

// ---------------------------------------------------------------------------
extern "C" void kernel_launch(void* const* d_in, const int* in_sizes, int n_in,
                              void* d_out, int out_size, void* d_ws,
                              size_t ws_size, hipStream_t stream) {
  const float* node_feats = (const float*)d_in[0];
  const float* edge_feats = (const float*)d_in[1];
  const int* senders = (const int*)d_in[2];
  const int* receivers = (const int*)d_in[3];
  auto f = [&](int i) { return (const float*)d_in[i]; };

  float* nodes = (float*)d_ws;             // NN x L f32
  float* edges = nodes + (size_t)NN * L;   // NE x L f32
  float* agg = edges + (size_t)NE * L;     // NN x L f32
  short* en_W1p = (short*)(agg + (size_t)NN * L);
  short* ee_W1p = en_W1p + 65536;
  short* pe_W0p = ee_W1p + 65536;          // 4 x 768 x 256
  short* pe_W1p = pe_W0p + 4 * 768 * 256;  // 4 x 256 x 256
  short* pn_W0p = pe_W1p + 4 * 65536;      // 4 x 512 x 256
  short* pn_W1p = pn_W0p + 4 * 512 * 256;  // 4 x 256 x 256
  short* dn_W0p = pn_W1p + 4 * 65536;      // 256 x 256
  short* dn_W1p = dn_W0p + 65536;          // 256 x 128

  pack_w<<<256, 256, 0, stream>>>(f(6), en_W1p, 256, 256, 1);
  pack_w<<<256, 256, 0, stream>>>(f(12), ee_W1p, 256, 256, 1);
  pack_w<<<1024, 256, 0, stream>>>(f(16), pe_W0p, 768, 256, 4);
  pack_w<<<512, 256, 0, stream>>>(f(18), pe_W1p, 256, 256, 4);
  pack_w<<<1024, 256, 0, stream>>>(f(22), pn_W0p, 512, 256, 4);
  pack_w<<<512, 256, 0, stream>>>(f(24), pn_W1p, 256, 256, 4);
  pack_w<<<256, 256, 0, stream>>>(f(28), dn_W0p, 256, 256, 1);
  pack_w<<<128, 256, 0, stream>>>(f(30), dn_W1p, 256, 128, 1);

  embed_mfma<3><<<NN / 64, 256, 0, stream>>>(node_feats, f(4), f(5), en_W1p,
                                             f(7), f(8), f(9), nodes);
  embed_mfma<4><<<NE / 64, 256, 0, stream>>>(edge_feats, f(10), f(11), ee_W1p,
                                             f(13), f(14), f(15), edges);

  for (int s = 0; s < SSTEPS; ++s) {
    hipMemsetAsync(agg, 0, (size_t)NN * L * sizeof(float), stream);
    edge_step_mfma<<<NE / 64, 256, 0, stream>>>(
        nodes, edges, agg, senders, receivers,
        pe_W0p + (size_t)s * 768 * 256, f(17) + (size_t)s * 256,
        pe_W1p + (size_t)s * 65536, f(19) + (size_t)s * 256,
        f(20) + (size_t)s * 256, f(21) + (size_t)s * 256);
    node_step_mfma<<<NN / 64, 256, 0, stream>>>(
        nodes, agg, pn_W0p + (size_t)s * 512 * 256, f(23) + (size_t)s * 256,
        pn_W1p + (size_t)s * 65536, f(25) + (size_t)s * 256,
        f(26) + (size_t)s * 256, f(27) + (size_t)s * 256);
  }

  decoder_mfma<<<NN / 64, 256, 0, stream>>>(nodes, dn_W0p, f(29), dn_W1p,
                                            f(31), (float*)d_out);
}

// Round 5
// 1336.470 us; speedup vs baseline: 5.4051x; 1.1225x over previous
//
#include <hip/hip_runtime.h>
#include <hip/hip_bf16.h>

#define NN 16384
#define NE 131072
#define L 256
#define SSTEPS 4
#define OUTD 128

typedef __attribute__((ext_vector_type(8))) short bf16x8;
typedef __attribute__((ext_vector_type(4))) float f32x4;

__device__ __forceinline__ short f2bs(float f) {
  unsigned u = __builtin_bit_cast(unsigned, f);
  u = (u + 0x7fffu + ((u >> 16) & 1u)) >> 16;
  return (short)u;
}
__device__ __forceinline__ float bs2f(short s) {
  unsigned u = ((unsigned)(unsigned short)s) << 16;
  return __builtin_bit_cast(float, u);
}
__device__ __forceinline__ float wave_sum(float v) {
#pragma unroll
  for (int o = 32; o > 0; o >>= 1) v += __shfl_xor(v, o);
  return v;
}

// Store one 16x16 C-tile (f32x4 per lane) into swizzled bf16 LDS [64][256]
// (row stride 512B). byte ^= (row&7)<<4.
__device__ __forceinline__ void store_tile(short* hs, int l, int mi, int nb,
                                           f32x4 v) {
  const int lm = l & 15, g = l >> 4;
#pragma unroll
  for (int i = 0; i < 4; ++i) {
    const float mine = v[i];
    const float part = __shfl_xor(mine, 1);
    if ((l & 1) == 0) {
      const int row = mi * 16 + g * 4 + i;
      const int col = nb + lm;  // even
      const unsigned pk = (unsigned)(unsigned short)f2bs(mine) |
                          ((unsigned)(unsigned short)f2bs(part) << 16);
      const int off = (row * 512 + col * 2) ^ ((row & 7) << 4);
      *(unsigned*)((char*)hs + off) = pk;
    }
  }
}

// GEMM from swizzled bf16 LDS h[64][256] (512B stride) x packed W (K=256).
template <int NT>
__device__ __forceinline__ void gemm2_lds(const short* __restrict__ Wp,
                                          int Ncols, const short* hs, int n0,
                                          int l, f32x4 acc[4][NT]) {
  const int lm = l & 15, g = l >> 4;
#pragma unroll
  for (int kc = 0; kc < 8; ++kc) {
    bf16x8 a[4];
#pragma unroll
    for (int mi = 0; mi < 4; ++mi) {
      const int row = mi * 16 + lm;
      const int off = (row * 512 + kc * 64 + g * 16) ^ ((row & 7) << 4);
      a[mi] = *(const bf16x8*)((const char*)hs + off);
    }
#pragma unroll
    for (int ni = 0; ni < NT; ++ni) {
      const int n = n0 + ni * 16 + lm;
      bf16x8 b = *(const bf16x8*)(Wp + ((size_t)kc * Ncols + n) * 32 + g * 8);
#pragma unroll
      for (int mi = 0; mi < 4; ++mi)
        acc[mi][ni] =
            __builtin_amdgcn_mfma_f32_16x16x32_bf16(a[mi], b, acc[mi][ni], 0, 0, 0);
    }
  }
}

// Pack fp32 weight [K][N] (cnt stacked) into bf16 Wp[k/32][n][k%32].
__global__ void pack_w(const float* __restrict__ src, short* __restrict__ dst,
                       int K, int N, int cnt) {
  const size_t total = (size_t)K * N * cnt;
  for (size_t i = (size_t)blockIdx.x * blockDim.x + threadIdx.x; i < total;
       i += (size_t)gridDim.x * blockDim.x) {
    const size_t mat = i / ((size_t)K * N);
    const int rem = (int)(i - mat * (size_t)K * N);
    const int k = rem / N, n = rem - k * N;
    dst[mat * (size_t)K * N + ((size_t)(k >> 5) * N + n) * 32 + (k & 31)] =
        f2bs(src[i]);
  }
}

// Layer-1 MFMA over one staged 128-K chunk in As (row stride 256B, swizzled).
__device__ __forceinline__ void mfma_chunk(const short* __restrict__ As,
                                           const short* __restrict__ W0p,
                                           int kcg_base, int w, int l,
                                           f32x4 acc[4][4]) {
  const int lm = l & 15, g = l >> 4;
#pragma unroll
  for (int kc = 0; kc < 4; ++kc) {
    bf16x8 a[4];
#pragma unroll
    for (int mi = 0; mi < 4; ++mi) {
      const int row = mi * 16 + lm;
      const int off = (row * 256 + kc * 64 + g * 16) ^ ((row & 7) << 4);
      a[mi] = *(const bf16x8*)((const char*)As + off);
    }
#pragma unroll
    for (int ni = 0; ni < 4; ++ni) {
      const int n = w * 64 + ni * 16 + lm;
      bf16x8 b =
          *(const bf16x8*)(W0p + ((size_t)(kcg_base + kc) * L + n) * 32 + g * 8);
#pragma unroll
      for (int mi = 0; mi < 4; ++mi)
        acc[mi][ni] =
            __builtin_amdgcn_mfma_f32_16x16x32_bf16(a[mi], b, acc[mi][ni], 0, 0, 0);
    }
  }
}

// ---------------------------------------------------------------------------
// CSR build (deterministic: per-node lists sorted ascending by edge id)
// ---------------------------------------------------------------------------
__global__ void csr_hist(const int* __restrict__ recv, int* __restrict__ deg) {
  const int e = blockIdx.x * 256 + threadIdx.x;
  atomicAdd(&deg[recv[e]], 1);
}
__global__ __launch_bounds__(256) void csr_scan(const int* __restrict__ deg,
                                                int* __restrict__ start,
                                                int* __restrict__ cursor) {
  __shared__ int part[256];
  const int t = threadIdx.x;
  int s = 0;
  for (int i = 0; i < NN / 256; ++i) s += deg[t * (NN / 256) + i];
  part[t] = s;
  __syncthreads();
  if (t == 0) {
    int acc = 0;
    for (int i = 0; i < 256; ++i) {
      const int v = part[i];
      part[i] = acc;
      acc += v;
    }
  }
  __syncthreads();
  int acc = part[t];
  for (int i = 0; i < NN / 256; ++i) {
    const int n = t * (NN / 256) + i;
    start[n] = acc;
    cursor[n] = acc;
    acc += deg[n];
  }
  if (t == 255) start[NN] = acc;
}
__global__ void csr_scatter(const int* __restrict__ recv,
                            int* __restrict__ cursor, int* __restrict__ elist) {
  const int e = blockIdx.x * 256 + threadIdx.x;
  const int p = atomicAdd(&cursor[recv[e]], 1);
  elist[p] = e;
}
__global__ void csr_sort(const int* __restrict__ start, int* __restrict__ elist) {
  const int n = blockIdx.x * blockDim.x + threadIdx.x;
  if (n >= NN) return;
  const int b = start[n], e = start[n + 1];
  for (int i = b + 1; i < e; ++i) {
    const int v = elist[i];
    int j = i - 1;
    while (j >= b && elist[j] > v) {
      elist[j + 1] = elist[j];
      --j;
    }
    elist[j + 1] = v;
  }
}

// ---------------------------------------------------------------------------
// agg gather: agg_b[n] = bf16( sum_{e in CSR[n]} new_e[e] )  (fp32 accum)
// ---------------------------------------------------------------------------
__global__ __launch_bounds__(256) void agg_gather(
    const short* __restrict__ new_e, const int* __restrict__ start,
    const int* __restrict__ elist, short* __restrict__ agg_b) {
  const int t = threadIdx.x, w = t >> 6, l = t & 63;
  const int n0 = blockIdx.x * 64;
  for (int i = 0; i < 16; ++i) {
    const int n = n0 + w * 16 + i;
    const int b = start[n], e = start[n + 1];
    float acc[4] = {0.f, 0.f, 0.f, 0.f};
    for (int j = b; j < e; ++j) {
      const int eid = elist[j];
      const short4 v = *(const short4*)(new_e + (size_t)eid * L + l * 4);
      acc[0] += bs2f(v.x);
      acc[1] += bs2f(v.y);
      acc[2] += bs2f(v.z);
      acc[3] += bs2f(v.w);
    }
    short4 o;
    o.x = f2bs(acc[0]);
    o.y = f2bs(acc[1]);
    o.z = f2bs(acc[2]);
    o.w = f2bs(acc[3]);
    *(short4*)(agg_b + (size_t)n * L + l * 4) = o;
  }
}

// ---------------------------------------------------------------------------
// Edge step: X=[edges_b|nodes_b[snd]|nodes_b[rcv]] (768 bf16) -> MFMA MLP ->
// LN -> edges_b += ne (bf16 master); new_e = ne (bf16). No atomics.
// ---------------------------------------------------------------------------
__global__ __launch_bounds__(256) void edge_step_mfma(
    const short* __restrict__ nodes_b, short* __restrict__ edges_b,
    short* __restrict__ new_e, const int* __restrict__ senders,
    const int* __restrict__ receivers, const short* __restrict__ W0p,
    const float* __restrict__ b0, const short* __restrict__ W1p,
    const float* __restrict__ b1, const float* __restrict__ ls,
    const float* __restrict__ lb) {
  __shared__ short smem[64 * 256];  // 32KB: As[2][64][128] then h/y[64][256]
  __shared__ int sn_s[64], rc_s[64];
  const int t = threadIdx.x, w = t >> 6, l = t & 63;
  const int lm = l & 15, g = l >> 4;
  const int tr = t >> 4, seg = t & 15;
  const int e0 = blockIdx.x * 64;
  short* As0 = smem;
  short* As1 = smem + 8192;

  if (t < 64) sn_s[t] = senders[e0 + t];
  else if (t < 128) rc_s[t - 64] = receivers[e0 + t - 64];

  bf16x8 o8[4];
  // prologue: chunk 0 (edges, bf16 cols 0..127)
#pragma unroll
  for (int p = 0; p < 4; ++p)
    o8[p] = *(const bf16x8*)(edges_b + (size_t)(e0 + p * 16 + tr) * L + seg * 8);
#pragma unroll
  for (int p = 0; p < 4; ++p) {
    const int row = p * 16 + tr;
    const int off = (row * 256 + seg * 16) ^ ((row & 7) << 4);
    *(bf16x8*)((char*)As0 + off) = o8[p];
  }
  __syncthreads();

  f32x4 acc[4][4] = {};
#pragma unroll
  for (int c = 0; c < 6; ++c) {
    if (c + 1 < 6) {  // issue next chunk's global loads (hide under MFMA)
      const int cn = c + 1;
      const short* src;
      const int* ridx = nullptr;
      int cb, rb = 0;
      if (cn < 2) { src = edges_b; cb = cn * 128; rb = e0; }
      else if (cn < 4) { src = nodes_b; cb = (cn - 2) * 128; ridx = sn_s; }
      else { src = nodes_b; cb = (cn - 4) * 128; ridx = rc_s; }
#pragma unroll
      for (int p = 0; p < 4; ++p) {
        const int row = p * 16 + tr;
        const size_t gr = ridx ? (size_t)ridx[row] : (size_t)(rb + row);
        o8[p] = *(const bf16x8*)(src + gr * L + cb + seg * 8);
      }
    }
    mfma_chunk((c & 1) ? As1 : As0, W0p, c * 4, w, l, acc);
    if (c + 1 < 6) {
      short* dbuf = (c & 1) ? As0 : As1;
#pragma unroll
      for (int p = 0; p < 4; ++p) {
        const int row = p * 16 + tr;
        const int off = (row * 256 + seg * 16) ^ ((row & 7) << 4);
        *(bf16x8*)((char*)dbuf + off) = o8[p];
      }
    }
    __syncthreads();
  }

  // bias + relu -> h in smem (viewed as [64][256], 512B stride)
#pragma unroll
  for (int ni = 0; ni < 4; ++ni) {
    const float bia = b0[w * 64 + ni * 16 + lm];
#pragma unroll
    for (int mi = 0; mi < 4; ++mi) {
      f32x4 v = acc[mi][ni];
#pragma unroll
      for (int i = 0; i < 4; ++i) v[i] = fmaxf(v[i] + bia, 0.f);
      store_tile(smem, l, mi, w * 64 + ni * 16, v);
    }
  }
  __syncthreads();

  f32x4 acc2[4][4] = {};
  gemm2_lds<4>(W1p, L, smem, w * 64, l, acc2);
  __syncthreads();
#pragma unroll
  for (int ni = 0; ni < 4; ++ni) {
    const float bia = b1[w * 64 + ni * 16 + lm];
#pragma unroll
    for (int mi = 0; mi < 4; ++mi) {
      f32x4 v = acc2[mi][ni];
#pragma unroll
      for (int i = 0; i < 4; ++i) v[i] += bia;
      store_tile(smem, l, mi, w * 64 + ni * 16, v);
    }
  }
  __syncthreads();

  float ls4[4], lb4[4];
#pragma unroll
  for (int j = 0; j < 4; ++j) {
    ls4[j] = ls[l + 64 * j];
    lb4[j] = lb[l + 64 * j];
  }
#pragma unroll 4
  for (int rr = 0; rr < 16; ++rr) {
    const int r = w * 16 + rr;
    float v[4];
#pragma unroll
    for (int j = 0; j < 4; ++j) {
      const int off = (r * 512 + (l + 64 * j) * 2) ^ ((r & 7) << 4);
      v[j] = bs2f(*(const short*)((const char*)smem + off));
    }
    const float mu = wave_sum(v[0] + v[1] + v[2] + v[3]) * (1.f / 256.f);
    float sq = 0.f;
#pragma unroll
    for (int j = 0; j < 4; ++j) {
      v[j] -= mu;
      sq += v[j] * v[j];
    }
    const float rstd = rsqrtf(wave_sum(sq) * (1.f / 256.f) + 1e-6f);
    const size_t e = (size_t)(e0 + r);
    short* eb = edges_b + e * L;
    short* nb = new_e + e * L;
#pragma unroll
    for (int j = 0; j < 4; ++j) {
      const int c = l + 64 * j;
      const float ne = v[j] * rstd * ls4[j] + lb4[j];
      eb[c] = f2bs(bs2f(eb[c]) + ne);  // bf16 residual master
      nb[c] = f2bs(ne);
    }
  }
}

// ---------------------------------------------------------------------------
// Node step: X=[nodes_b|agg_b] (512 bf16) -> MFMA MLP -> LN ->
// nodes_f += ne (fp32 master) ; nodes_b = bf16(nodes_f)
// ---------------------------------------------------------------------------
__global__ __launch_bounds__(256) void node_step_mfma(
    float* __restrict__ nodes_f, short* __restrict__ nodes_b,
    const short* __restrict__ agg_b, const short* __restrict__ W0p,
    const float* __restrict__ b0, const short* __restrict__ W1p,
    const float* __restrict__ b1, const float* __restrict__ ls,
    const float* __restrict__ lb) {
  __shared__ short smem[64 * 256];
  const int t = threadIdx.x, w = t >> 6, l = t & 63;
  const int lm = l & 15, g = l >> 4;
  const int tr = t >> 4, seg = t & 15;
  const int n0 = blockIdx.x * 64;
  short* As0 = smem;
  short* As1 = smem + 8192;

  bf16x8 o8[4];
#pragma unroll
  for (int p = 0; p < 4; ++p)
    o8[p] = *(const bf16x8*)(nodes_b + (size_t)(n0 + p * 16 + tr) * L + seg * 8);
#pragma unroll
  for (int p = 0; p < 4; ++p) {
    const int row = p * 16 + tr;
    const int off = (row * 256 + seg * 16) ^ ((row & 7) << 4);
    *(bf16x8*)((char*)As0 + off) = o8[p];
  }
  __syncthreads();

  f32x4 acc[4][4] = {};
#pragma unroll
  for (int c = 0; c < 4; ++c) {
    if (c + 1 < 4) {
      const int cn = c + 1;
      const short* src = (cn < 2) ? nodes_b : agg_b;
      const int cb = (cn & 1) * 128;
#pragma unroll
      for (int p = 0; p < 4; ++p)
        o8[p] = *(const bf16x8*)(src + (size_t)(n0 + p * 16 + tr) * L + cb + seg * 8);
    }
    mfma_chunk((c & 1) ? As1 : As0, W0p, c * 4, w, l, acc);
    if (c + 1 < 4) {
      short* dbuf = (c & 1) ? As0 : As1;
#pragma unroll
      for (int p = 0; p < 4; ++p) {
        const int row = p * 16 + tr;
        const int off = (row * 256 + seg * 16) ^ ((row & 7) << 4);
        *(bf16x8*)((char*)dbuf + off) = o8[p];
      }
    }
    __syncthreads();
  }

#pragma unroll
  for (int ni = 0; ni < 4; ++ni) {
    const float bia = b0[w * 64 + ni * 16 + lm];
#pragma unroll
    for (int mi = 0; mi < 4; ++mi) {
      f32x4 v = acc[mi][ni];
#pragma unroll
      for (int i = 0; i < 4; ++i) v[i] = fmaxf(v[i] + bia, 0.f);
      store_tile(smem, l, mi, w * 64 + ni * 16, v);
    }
  }
  __syncthreads();

  f32x4 acc2[4][4] = {};
  gemm2_lds<4>(W1p, L, smem, w * 64, l, acc2);
  __syncthreads();
#pragma unroll
  for (int ni = 0; ni < 4; ++ni) {
    const float bia = b1[w * 64 + ni * 16 + lm];
#pragma unroll
    for (int mi = 0; mi < 4; ++mi) {
      f32x4 v = acc2[mi][ni];
#pragma unroll
      for (int i = 0; i < 4; ++i) v[i] += bia;
      store_tile(smem, l, mi, w * 64 + ni * 16, v);
    }
  }
  __syncthreads();

  float ls4[4], lb4[4];
#pragma unroll
  for (int j = 0; j < 4; ++j) {
    ls4[j] = ls[l + 64 * j];
    lb4[j] = lb[l + 64 * j];
  }
#pragma unroll 4
  for (int rr = 0; rr < 16; ++rr) {
    const int r = w * 16 + rr;
    float v[4];
#pragma unroll
    for (int j = 0; j < 4; ++j) {
      const int off = (r * 512 + (l + 64 * j) * 2) ^ ((r & 7) << 4);
      v[j] = bs2f(*(const short*)((const char*)smem + off));
    }
    const float mu = wave_sum(v[0] + v[1] + v[2] + v[3]) * (1.f / 256.f);
    float sq = 0.f;
#pragma unroll
    for (int j = 0; j < 4; ++j) {
      v[j] -= mu;
      sq += v[j] * v[j];
    }
    const float rstd = rsqrtf(wave_sum(sq) * (1.f / 256.f) + 1e-6f);
    float* nf = nodes_f + (size_t)(n0 + r) * L;
    short* nb = nodes_b + (size_t)(n0 + r) * L;
#pragma unroll
    for (int j = 0; j < 4; ++j) {
      const int c = l + 64 * j;
      const float nv = nf[c] + (v[j] * rstd * ls4[j] + lb4[j]);
      nf[c] = nv;
      nb[c] = f2bs(nv);
    }
  }
}

// ---------------------------------------------------------------------------
// Embedder: layer1 (K1->256, VALU) -> h in LDS -> MFMA layer2 -> LN -> dst
// WF32: also write fp32 master (nodes); always writes bf16.
// ---------------------------------------------------------------------------
template <int K1, bool WF32>
__global__ __launch_bounds__(256) void embed_mfma(
    const float* __restrict__ x, const float* __restrict__ W0,
    const float* __restrict__ b0, const short* __restrict__ W1p,
    const float* __restrict__ b1, const float* __restrict__ ls,
    const float* __restrict__ lb, float* __restrict__ dst_f,
    short* __restrict__ dst_b) {
  __shared__ short hs[64 * 256];
  __shared__ float xs[64][K1];
  const int t = threadIdx.x, w = t >> 6, l = t & 63;
  const int r0 = blockIdx.x * 64;

  if (t < 64 * K1) xs[t / K1][t % K1] = x[(size_t)r0 * K1 + t];
  __syncthreads();

  float wc[K1];
#pragma unroll
  for (int k = 0; k < K1; ++k) wc[k] = W0[k * L + t];
  const float bb = b0[t];
  for (int r = 0; r < 64; ++r) {
    float h = bb;
#pragma unroll
    for (int k = 0; k < K1; ++k) h = fmaf(xs[r][k], wc[k], h);
    h = fmaxf(h, 0.f);
    const int off = (r * 512 + t * 2) ^ ((r & 7) << 4);
    *(short*)((char*)hs + off) = f2bs(h);
  }
  __syncthreads();

  const int lm = l & 15;
  f32x4 acc2[4][4] = {};
  gemm2_lds<4>(W1p, L, hs, w * 64, l, acc2);
  __syncthreads();
#pragma unroll
  for (int ni = 0; ni < 4; ++ni) {
    const float bia = b1[w * 64 + ni * 16 + lm];
#pragma unroll
    for (int mi = 0; mi < 4; ++mi) {
      f32x4 v = acc2[mi][ni];
#pragma unroll
      for (int i = 0; i < 4; ++i) v[i] += bia;
      store_tile(hs, l, mi, w * 64 + ni * 16, v);
    }
  }
  __syncthreads();

  float ls4[4], lb4[4];
#pragma unroll
  for (int j = 0; j < 4; ++j) {
    ls4[j] = ls[l + 64 * j];
    lb4[j] = lb[l + 64 * j];
  }
#pragma unroll 4
  for (int rr = 0; rr < 16; ++rr) {
    const int r = w * 16 + rr;
    float v[4];
#pragma unroll
    for (int j = 0; j < 4; ++j) {
      const int off = (r * 512 + (l + 64 * j) * 2) ^ ((r & 7) << 4);
      v[j] = bs2f(*(const short*)((const char*)hs + off));
    }
    const float mu = wave_sum(v[0] + v[1] + v[2] + v[3]) * (1.f / 256.f);
    float sq = 0.f;
#pragma unroll
    for (int j = 0; j < 4; ++j) {
      v[j] -= mu;
      sq += v[j] * v[j];
    }
    const float rstd = rsqrtf(wave_sum(sq) * (1.f / 256.f) + 1e-6f);
    float* df = WF32 ? dst_f + (size_t)(r0 + r) * L : nullptr;
    short* db = dst_b + (size_t)(r0 + r) * L;
#pragma unroll
    for (int j = 0; j < 4; ++j) {
      const int c = l + 64 * j;
      const float val = v[j] * rstd * ls4[j] + lb4[j];
      if (WF32) df[c] = val;
      db[c] = f2bs(val);
    }
  }
}

// ---------------------------------------------------------------------------
// Decoder: nodes_b (256 bf16) -> MFMA 256 relu -> MFMA 128 -> out (fp32)
// ---------------------------------------------------------------------------
__global__ __launch_bounds__(256) void decoder_mfma(
    const short* __restrict__ nodes_b, const short* __restrict__ W0p,
    const float* __restrict__ b0, const short* __restrict__ W1p,
    const float* __restrict__ b1, float* __restrict__ out) {
  __shared__ short hs[64 * 256];
  const int t = threadIdx.x, w = t >> 6, l = t & 63;
  const int lm = l & 15, g = l >> 4;
  const int n0 = blockIdx.x * 64;

  const short* baseA[4];
#pragma unroll
  for (int mi = 0; mi < 4; ++mi)
    baseA[mi] = nodes_b + (size_t)(n0 + mi * 16 + lm) * L;

  f32x4 acc[4][4] = {};
#pragma unroll
  for (int kc = 0; kc < 8; ++kc) {
    const int koff = kc * 32 + g * 8;
    bf16x8 a[4];
#pragma unroll
    for (int mi = 0; mi < 4; ++mi) a[mi] = *(const bf16x8*)(baseA[mi] + koff);
#pragma unroll
    for (int ni = 0; ni < 4; ++ni) {
      const int n = w * 64 + ni * 16 + lm;
      bf16x8 b = *(const bf16x8*)(W0p + ((size_t)kc * L + n) * 32 + g * 8);
#pragma unroll
      for (int mi = 0; mi < 4; ++mi)
        acc[mi][ni] = __builtin_amdgcn_mfma_f32_16x16x32_bf16(a[mi], b,
                                                             acc[mi][ni],
                                                             0, 0, 0);
    }
  }
#pragma unroll
  for (int ni = 0; ni < 4; ++ni) {
    const float bia = b0[w * 64 + ni * 16 + lm];
#pragma unroll
    for (int mi = 0; mi < 4; ++mi) {
      f32x4 v = acc[mi][ni];
#pragma unroll
      for (int i = 0; i < 4; ++i) v[i] = fmaxf(v[i] + bia, 0.f);
      store_tile(hs, l, mi, w * 64 + ni * 16, v);
    }
  }
  __syncthreads();

  f32x4 acc2[4][2] = {};
  gemm2_lds<2>(W1p, OUTD, hs, w * 32, l, acc2);

  float b14[2];
#pragma unroll
  for (int ni = 0; ni < 2; ++ni) b14[ni] = b1[w * 32 + ni * 16 + lm];
#pragma unroll
  for (int mi = 0; mi < 4; ++mi)
#pragma unroll
    for (int ni = 0; ni < 2; ++ni)
#pragma unroll
      for (int i = 0; i < 4; ++i) {
        const int row = n0 + mi * 16 + g * 4 + i;
        const int col = w * 32 + ni * 16 + lm;
        out[(size_t)row * OUTD + col] = acc2[mi][ni][i] + b14[ni];
      }
}

// ---------------------------------------------------------------------------
extern "C" void kernel_launch(void* const* d_in, const int* in_sizes, int n_in,
                              void* d_out, int out_size, void* d_ws,
                              size_t ws_size, hipStream_t stream) {
  const float* node_feats = (const float*)d_in[0];
  const float* edge_feats = (const float*)d_in[1];
  const int* senders = (const int*)d_in[2];
  const int* receivers = (const int*)d_in[3];
  auto f = [&](int i) { return (const float*)d_in[i]; };

  char* p = (char*)d_ws;
  auto alloc = [&](size_t bytes) {
    char* q = p;
    p += (bytes + 255) & ~(size_t)255;
    return q;
  };
  float* nodes_f = (float*)alloc((size_t)NN * L * 4);   // 16 MB
  short* nodes_b = (short*)alloc((size_t)NN * L * 2);   // 8 MB
  short* edges_b = (short*)alloc((size_t)NE * L * 2);   // 67 MB
  short* new_e = (short*)alloc((size_t)NE * L * 2);     // 67 MB
  short* agg_b = (short*)alloc((size_t)NN * L * 2);     // 8 MB
  int* deg = (int*)alloc((size_t)NN * 4);
  int* start = (int*)alloc((size_t)(NN + 16) * 4);
  int* cursor = (int*)alloc((size_t)NN * 4);
  int* elist = (int*)alloc((size_t)NE * 4);
  short* en_W1p = (short*)alloc(65536 * 2);
  short* ee_W1p = (short*)alloc(65536 * 2);
  short* pe_W0p = (short*)alloc((size_t)4 * 768 * 256 * 2);
  short* pe_W1p = (short*)alloc((size_t)4 * 65536 * 2);
  short* pn_W0p = (short*)alloc((size_t)4 * 512 * 256 * 2);
  short* pn_W1p = (short*)alloc((size_t)4 * 65536 * 2);
  short* dn_W0p = (short*)alloc(65536 * 2);
  short* dn_W1p = (short*)alloc(32768 * 2);

  // CSR build (deterministic after per-node sort)
  hipMemsetAsync(deg, 0, (size_t)NN * 4, stream);
  csr_hist<<<NE / 256, 256, 0, stream>>>(receivers, deg);
  csr_scan<<<1, 256, 0, stream>>>(deg, start, cursor);
  csr_scatter<<<NE / 256, 256, 0, stream>>>(receivers, cursor, elist);
  csr_sort<<<NN / 256, 256, 0, stream>>>(start, elist);

  pack_w<<<256, 256, 0, stream>>>(f(6), en_W1p, 256, 256, 1);
  pack_w<<<256, 256, 0, stream>>>(f(12), ee_W1p, 256, 256, 1);
  pack_w<<<1024, 256, 0, stream>>>(f(16), pe_W0p, 768, 256, 4);
  pack_w<<<512, 256, 0, stream>>>(f(18), pe_W1p, 256, 256, 4);
  pack_w<<<1024, 256, 0, stream>>>(f(22), pn_W0p, 512, 256, 4);
  pack_w<<<512, 256, 0, stream>>>(f(24), pn_W1p, 256, 256, 4);
  pack_w<<<256, 256, 0, stream>>>(f(28), dn_W0p, 256, 256, 1);
  pack_w<<<128, 256, 0, stream>>>(f(30), dn_W1p, 256, 128, 1);

  embed_mfma<3, true><<<NN / 64, 256, 0, stream>>>(
      node_feats, f(4), f(5), en_W1p, f(7), f(8), f(9), nodes_f, nodes_b);
  embed_mfma<4, false><<<NE / 64, 256, 0, stream>>>(
      edge_feats, f(10), f(11), ee_W1p, f(13), f(14), f(15), nullptr, edges_b);

  for (int s = 0; s < SSTEPS; ++s) {
    edge_step_mfma<<<NE / 64, 256, 0, stream>>>(
        nodes_b, edges_b, new_e, senders, receivers,
        pe_W0p + (size_t)s * 768 * 256, f(17) + (size_t)s * 256,
        pe_W1p + (size_t)s * 65536, f(19) + (size_t)s * 256,
        f(20) + (size_t)s * 256, f(21) + (size_t)s * 256);
    agg_gather<<<NN / 64, 256, 0, stream>>>(new_e, start, elist, agg_b);
    node_step_mfma<<<NN / 64, 256, 0, stream>>>(
        nodes_f, nodes_b, agg_b, pn_W0p + (size_t)s * 512 * 256,
        f(23) + (size_t)s * 256, pn_W1p + (size_t)s * 65536,
        f(25) + (size_t)s * 256, f(26) + (size_t)s * 256,
        f(27) + (size_t)s * 256);
  }

  decoder_mfma<<<NN / 64, 256, 0, stream>>>(nodes_b, dn_W0p, f(29), dn_W1p,
                                            f(31), (float*)d_out);
}